// Round 1
// baseline (314.302 us; speedup 1.0000x reference)
//
#include <hip/hip_runtime.h>

// MHA: B=4, S=1024, D=1024, H=16, DK=64
// Pipeline: cvt(f32->bf16) x7, mask->bits, fused QKV GEMM (bf16 MFMA),
// flash attention, output GEMM (fp32 out).

typedef __attribute__((ext_vector_type(8))) short short8;
typedef __attribute__((ext_vector_type(4))) float f32x4;
typedef __attribute__((ext_vector_type(4))) unsigned short u16x4;

__device__ __forceinline__ unsigned short f2bf(float f) {
    unsigned u = __float_as_uint(f);
    unsigned r = (u + 0x7FFFu + ((u >> 16) & 1u)) >> 16;
    return (unsigned short)r;
}

// ---------------- convert fp32 -> bf16 (vectorized) ----------------
__global__ __launch_bounds__(256) void cvt_f32_bf16(const float* __restrict__ in,
                                                    unsigned short* __restrict__ out,
                                                    int n4) {
    int i = blockIdx.x * 256 + threadIdx.x;
    if (i >= n4) return;
    f32x4 v = ((const f32x4*)in)[i];
    u16x4 r;
    r.x = f2bf(v.x); r.y = f2bf(v.y); r.z = f2bf(v.z); r.w = f2bf(v.w);
    ((u16x4*)out)[i] = r;
}

// ---------------- mask int32 -> bitmask via ballot ----------------
__global__ __launch_bounds__(256) void mask_to_bits(const int* __restrict__ m,
                                                    unsigned long long* __restrict__ bits) {
    int i = blockIdx.x * 256 + threadIdx.x;
    unsigned long long bal = __ballot(m[i] != 0);
    if ((threadIdx.x & 63) == 0) bits[i >> 6] = bal;
}

// ---------------- GEMM core: C[128x128] = A[128xK] * B[128xK]^T ----------------
// A: [M][K] bf16 row-major, B: [N][K] bf16 row-major (K-contiguous both).
// 256 threads = 4 waves, wave tile 64x64, BK=64, XOR-swizzled LDS (no pad).
__device__ __forceinline__ void gemm_core_128(const unsigned short* __restrict__ A,
                                              const unsigned short* __restrict__ B,
                                              int m0, int n0,
                                              unsigned short* As, unsigned short* Bs,
                                              f32x4 acc[4][4]) {
    const int t = threadIdx.x;
    const int lane = t & 63;
    const int wid = t >> 6;
    const int l15 = lane & 15;
    const int quad = lane >> 4;
    const int wm = (wid & 1) * 64;
    const int wn = (wid >> 1) * 64;
    const int sr = t >> 3;   // 0..31 staging row within pass
    const int sc = t & 7;    // 16B granule 0..7 within a 64-elem row

    for (int kt = 0; kt < 1024; kt += 64) {
        __syncthreads();
        // stage A and B tiles: 128 rows x 64 bf16 each; swizzle granule: sc^(r&7)
        #pragma unroll
        for (int p = 0; p < 4; ++p) {
            int r = p * 32 + sr;
            int gl = sc ^ (r & 7);
            *(short8*)&As[r * 64 + gl * 8] =
                *(const short8*)&A[(size_t)(m0 + r) * 1024 + kt + sc * 8];
            *(short8*)&Bs[r * 64 + gl * 8] =
                *(const short8*)&B[(size_t)(n0 + r) * 1024 + kt + sc * 8];
        }
        __syncthreads();
        #pragma unroll
        for (int ks = 0; ks < 2; ++ks) {
            short8 af[4], bf[4];
            #pragma unroll
            for (int i = 0; i < 4; ++i) {
                int mr = wm + i * 16 + l15;
                af[i] = *(const short8*)&As[mr * 64 + (((ks << 2) + quad) ^ (mr & 7)) * 8];
                int nr = wn + i * 16 + l15;
                bf[i] = *(const short8*)&Bs[nr * 64 + (((ks << 2) + quad) ^ (nr & 7)) * 8];
            }
            #pragma unroll
            for (int mi = 0; mi < 4; ++mi)
                #pragma unroll
                for (int ni = 0; ni < 4; ++ni)
                    acc[mi][ni] = __builtin_amdgcn_mfma_f32_16x16x32_bf16(
                        af[mi], bf[ni], acc[mi][ni], 0, 0, 0);
        }
    }
}

// ---------------- fused QKV projection GEMM ----------------
// grid.x = 24 (8 n-tiles x 3 problems), grid.y = 32 (m-tiles)
// p=0 -> Q [B,H,S,DK]; p=1 -> K [B,H,S,DK]; p=2 -> V^T [B,H,DK,S]
__global__ __launch_bounds__(256) void gemm_qkv(
    const unsigned short* __restrict__ Aq, const unsigned short* __restrict__ Ak,
    const unsigned short* __restrict__ Av,
    const unsigned short* __restrict__ Wq, const unsigned short* __restrict__ Wk,
    const unsigned short* __restrict__ Wv,
    const float* __restrict__ bq, const float* __restrict__ bk,
    const float* __restrict__ bv,
    unsigned short* __restrict__ Qo, unsigned short* __restrict__ Ko,
    unsigned short* __restrict__ VTo) {
    __shared__ unsigned short As[128 * 64];
    __shared__ unsigned short Bs[128 * 64];
    const int bn = blockIdx.x;
    const int p = bn >> 3;
    const int n0 = (bn & 7) * 128;
    const int m0 = blockIdx.y * 128;
    const unsigned short* A = (p == 0) ? Aq : ((p == 1) ? Ak : Av);
    const unsigned short* W = (p == 0) ? Wq : ((p == 1) ? Wk : Wv);
    const float* bias = (p == 0) ? bq : ((p == 1) ? bk : bv);

    f32x4 acc[4][4];
    #pragma unroll
    for (int i = 0; i < 4; ++i)
        #pragma unroll
        for (int j = 0; j < 4; ++j) acc[i][j] = (f32x4){0.f, 0.f, 0.f, 0.f};

    gemm_core_128(A, W, m0, n0, As, Bs, acc);

    const int lane = threadIdx.x & 63;
    const int wid = threadIdx.x >> 6;
    const int l15 = lane & 15;
    const int quad = lane >> 4;
    const int wm = (wid & 1) * 64;
    const int wn = (wid >> 1) * 64;
    unsigned short* dst01 = (p == 0) ? Qo : Ko;

    #pragma unroll
    for (int mi = 0; mi < 4; ++mi) {
        #pragma unroll
        for (int ni = 0; ni < 4; ++ni) {
            int col = n0 + wn + ni * 16 + l15;     // 0..1023
            int h = col >> 6, dk = col & 63;
            float bcol = bias[col];
            if (p < 2) {
                #pragma unroll
                for (int r = 0; r < 4; ++r) {
                    int row = m0 + wm + mi * 16 + quad * 4 + r;  // 0..4095
                    int bb = row >> 10, s = row & 1023;
                    dst01[(size_t)((bb * 16 + h) * 1024 + s) * 64 + dk] =
                        f2bf(acc[mi][ni][r] + bcol);
                }
            } else {
                int row0 = m0 + wm + mi * 16 + quad * 4;  // multiple of 4
                int bb = row0 >> 10, s0 = row0 & 1023;
                unsigned long long pk = 0;
                #pragma unroll
                for (int r = 0; r < 4; ++r)
                    pk |= (unsigned long long)f2bf(acc[mi][ni][r] + bcol) << (16 * r);
                *(unsigned long long*)&VTo[(size_t)((bb * 16 + h) * 64 + dk) * 1024 + s0] = pk;
            }
        }
    }
}

// ---------------- output projection GEMM (fp32 out) ----------------
__global__ __launch_bounds__(256) void gemm_out(
    const unsigned short* __restrict__ X, const unsigned short* __restrict__ Wo,
    const float* __restrict__ bo, float* __restrict__ out) {
    __shared__ unsigned short As[128 * 64];
    __shared__ unsigned short Bs[128 * 64];
    const int n0 = blockIdx.x * 128;
    const int m0 = blockIdx.y * 128;

    f32x4 acc[4][4];
    #pragma unroll
    for (int i = 0; i < 4; ++i)
        #pragma unroll
        for (int j = 0; j < 4; ++j) acc[i][j] = (f32x4){0.f, 0.f, 0.f, 0.f};

    gemm_core_128(X, Wo, m0, n0, As, Bs, acc);

    const int lane = threadIdx.x & 63;
    const int wid = threadIdx.x >> 6;
    const int l15 = lane & 15;
    const int quad = lane >> 4;
    const int wm = (wid & 1) * 64;
    const int wn = (wid >> 1) * 64;

    #pragma unroll
    for (int mi = 0; mi < 4; ++mi) {
        #pragma unroll
        for (int ni = 0; ni < 4; ++ni) {
            int col = n0 + wn + ni * 16 + l15;
            float bcol = bo[col];
            #pragma unroll
            for (int r = 0; r < 4; ++r) {
                int row = m0 + wm + mi * 16 + quad * 4 + r;
                out[(size_t)row * 1024 + col] = acc[mi][ni][r] + bcol;
            }
        }
    }
}

// ---------------- flash attention ----------------
// grid: (8 q-tiles, 16 heads, 4 batch). 256 threads = 4 waves.
// Q,K: [B,H,S,DK] bf16; VT: [B,H,DK,S] bf16. X out: [B,S,H*DK] bf16.
__global__ __launch_bounds__(256) void attn_kernel(
    const unsigned short* __restrict__ Q, const unsigned short* __restrict__ K,
    const unsigned short* __restrict__ VT,
    const unsigned long long* __restrict__ mbits,
    unsigned short* __restrict__ X) {
    __shared__ unsigned short Qs[128 * 64];  // q rows, swizzled
    __shared__ unsigned short Ks[64 * 64];   // kv rows, swizzled
    __shared__ unsigned short Vs[64 * 64];   // V^T: d rows x kv cols, swizzled
    __shared__ unsigned short Ps[4][32 * 72];  // per-wave P, padded stride 72

    const int qt = blockIdx.x;
    const int h = blockIdx.y;
    const int b = blockIdx.z;
    const int t = threadIdx.x;
    const int lane = t & 63;
    const int wid = t >> 6;
    const int l15 = lane & 15;
    const int quad = lane >> 4;
    const int wq = wid * 32;   // wave's q offset within the 128-row tile
    const int q0 = qt * 128;
    const int sr = t >> 3;
    const int sc = t & 7;

    const size_t headoff = (size_t)(b * 16 + h) * 1024 * 64;
    const unsigned short* Qh = Q + headoff;
    const unsigned short* Kh = K + headoff;
    const unsigned short* Vh = VT + headoff;  // [64][1024]

    // stage the Q tile once
    #pragma unroll
    for (int p = 0; p < 4; ++p) {
        int r = p * 32 + sr;
        int gl = sc ^ (r & 7);
        *(short8*)&Qs[r * 64 + gl * 8] =
            *(const short8*)&Qh[(size_t)(q0 + r) * 64 + sc * 8];
    }

    f32x4 o_acc[2][4];
    #pragma unroll
    for (int i = 0; i < 2; ++i)
        #pragma unroll
        for (int j = 0; j < 4; ++j) o_acc[i][j] = (f32x4){0.f, 0.f, 0.f, 0.f};
    float mrow[2][4], lrow[2][4];
    #pragma unroll
    for (int i = 0; i < 2; ++i)
        #pragma unroll
        for (int r = 0; r < 4; ++r) { mrow[i][r] = -3.0e38f; lrow[i][r] = 0.f; }

    for (int kt = 0; kt < 16; ++kt) {
        const int kv0 = kt * 64;
        __syncthreads();
        // stage K tile [64][64] and V^T tile [64 d][64 kv]
        #pragma unroll
        for (int p = 0; p < 2; ++p) {
            int r = p * 32 + sr;
            int gl = sc ^ (r & 7);
            *(short8*)&Ks[r * 64 + gl * 8] =
                *(const short8*)&Kh[(size_t)(kv0 + r) * 64 + sc * 8];
            *(short8*)&Vs[r * 64 + gl * 8] =
                *(const short8*)&Vh[(size_t)r * 1024 + kv0 + sc * 8];
        }
        __syncthreads();

        // S = Q K^T  (wave: 32 q-rows x 64 kv-cols)
        f32x4 sacc[2][4];
        #pragma unroll
        for (int i = 0; i < 2; ++i)
            #pragma unroll
            for (int j = 0; j < 4; ++j) sacc[i][j] = (f32x4){0.f, 0.f, 0.f, 0.f};
        #pragma unroll
        for (int ks = 0; ks < 2; ++ks) {
            short8 qf[2], kf[4];
            #pragma unroll
            for (int i = 0; i < 2; ++i) {
                int m = wq + i * 16 + l15;
                qf[i] = *(const short8*)&Qs[m * 64 + (((ks << 2) + quad) ^ (m & 7)) * 8];
            }
            #pragma unroll
            for (int j = 0; j < 4; ++j) {
                int n = j * 16 + l15;
                kf[j] = *(const short8*)&Ks[n * 64 + (((ks << 2) + quad) ^ (n & 7)) * 8];
            }
            #pragma unroll
            for (int mi = 0; mi < 2; ++mi)
                #pragma unroll
                for (int ni = 0; ni < 4; ++ni)
                    sacc[mi][ni] = __builtin_amdgcn_mfma_f32_16x16x32_bf16(
                        qf[mi], kf[ni], sacc[mi][ni], 0, 0, 0);
        }

        // mask + online softmax (rows: q = quad*4 + r within each 16-tile)
        #pragma unroll
        for (int mi = 0; mi < 2; ++mi) {
            int qbase = q0 + wq + mi * 16 + quad * 4;
            #pragma unroll
            for (int r = 0; r < 4; ++r) {
                unsigned long long w =
                    mbits[((size_t)((b << 10) + qbase + r) << 4) + kt];
                float mx = -3.0e38f;
                #pragma unroll
                for (int ni = 0; ni < 4; ++ni) {
                    float s = sacc[mi][ni][r] * 0.125f;
                    s = ((w >> (ni * 16 + l15)) & 1ull) ? s : -1.0e9f;
                    sacc[mi][ni][r] = s;
                    mx = fmaxf(mx, s);
                }
                mx = fmaxf(mx, __shfl_xor(mx, 1));
                mx = fmaxf(mx, __shfl_xor(mx, 2));
                mx = fmaxf(mx, __shfl_xor(mx, 4));
                mx = fmaxf(mx, __shfl_xor(mx, 8));
                float mnew = fmaxf(mrow[mi][r], mx);
                float alpha = __expf(mrow[mi][r] - mnew);
                mrow[mi][r] = mnew;
                float lsum = 0.f;
                #pragma unroll
                for (int ni = 0; ni < 4; ++ni) {
                    float pv = __expf(sacc[mi][ni][r] - mnew);
                    lsum += pv;
                    Ps[wid][(mi * 16 + quad * 4 + r) * 72 + ni * 16 + l15] = f2bf(pv);
                }
                lsum += __shfl_xor(lsum, 1);
                lsum += __shfl_xor(lsum, 2);
                lsum += __shfl_xor(lsum, 4);
                lsum += __shfl_xor(lsum, 8);
                lrow[mi][r] = lrow[mi][r] * alpha + lsum;
                #pragma unroll
                for (int ni = 0; ni < 4; ++ni) o_acc[mi][ni][r] *= alpha;
            }
        }

        // O += P V   (P from per-wave LDS in A-layout; V^T in B-layout)
        #pragma unroll
        for (int ks = 0; ks < 2; ++ks) {
            short8 pf[2], vf[4];
            #pragma unroll
            for (int i = 0; i < 2; ++i)
                pf[i] = *(const short8*)&Ps[wid][(i * 16 + l15) * 72 + ks * 32 + quad * 8];
            #pragma unroll
            for (int j = 0; j < 4; ++j) {
                int d = j * 16 + l15;
                vf[j] = *(const short8*)&Vs[d * 64 + (((ks << 2) + quad) ^ (d & 7)) * 8];
            }
            #pragma unroll
            for (int mi = 0; mi < 2; ++mi)
                #pragma unroll
                for (int ni = 0; ni < 4; ++ni)
                    o_acc[mi][ni] = __builtin_amdgcn_mfma_f32_16x16x32_bf16(
                        pf[mi], vf[ni], o_acc[mi][ni], 0, 0, 0);
        }
    }

    // normalize + store X[b][s][h*64+d] bf16
    #pragma unroll
    for (int mi = 0; mi < 2; ++mi) {
        #pragma unroll
        for (int r = 0; r < 4; ++r) {
            int q = q0 + wq + mi * 16 + quad * 4 + r;
            float inv = 1.0f / lrow[mi][r];
            #pragma unroll
            for (int ni = 0; ni < 4; ++ni) {
                X[(size_t)(b * 1024 + q) * 1024 + h * 64 + ni * 16 + l15] =
                    f2bf(o_acc[mi][ni][r] * inv);
            }
        }
    }
}

// ---------------- launch ----------------
extern "C" void kernel_launch(void* const* d_in, const int* in_sizes, int n_in,
                              void* d_out, int out_size, void* d_ws, size_t ws_size,
                              hipStream_t stream) {
    const float* query = (const float*)d_in[0];
    const float* key_ = (const float*)d_in[1];
    const float* value = (const float*)d_in[2];
    const int* mask = (const int*)d_in[3];
    const float* wq = (const float*)d_in[4];
    const float* bq = (const float*)d_in[5];
    const float* wk = (const float*)d_in[6];
    const float* bk = (const float*)d_in[7];
    const float* wv = (const float*)d_in[8];
    const float* bv = (const float*)d_in[9];
    const float* wo = (const float*)d_in[10];
    const float* bo = (const float*)d_in[11];
    float* out = (float*)d_out;

    char* ws = (char*)d_ws;
    const size_t XB = (size_t)4096 * 1024 * 2;  // 8 MB bf16 activation
    const size_t WB = (size_t)1024 * 1024 * 2;  // 2 MB bf16 weight
    unsigned short* xq = (unsigned short*)(ws);
    unsigned short* xk = (unsigned short*)(ws + XB);
    unsigned short* xv = (unsigned short*)(ws + 2 * XB);
    unsigned short* wqb = (unsigned short*)(ws + 3 * XB);
    unsigned short* wkb = (unsigned short*)(ws + 3 * XB + WB);
    unsigned short* wvb = (unsigned short*)(ws + 3 * XB + 2 * WB);
    unsigned short* wob = (unsigned short*)(ws + 3 * XB + 3 * WB);
    unsigned short* Qb = (unsigned short*)(ws + 3 * XB + 4 * WB);
    unsigned short* Kb = (unsigned short*)(ws + 4 * XB + 4 * WB);
    unsigned short* VTb = (unsigned short*)(ws + 5 * XB + 4 * WB);
    unsigned long long* bits = (unsigned long long*)(ws + 6 * XB + 4 * WB);
    unsigned short* Xattn = xq;  // alias: xq dead after gemm_qkv

    cvt_f32_bf16<<<4096, 256, 0, stream>>>(query, xq, 1048576);
    cvt_f32_bf16<<<4096, 256, 0, stream>>>(key_, xk, 1048576);
    cvt_f32_bf16<<<4096, 256, 0, stream>>>(value, xv, 1048576);
    cvt_f32_bf16<<<1024, 256, 0, stream>>>(wq, wqb, 262144);
    cvt_f32_bf16<<<1024, 256, 0, stream>>>(wk, wkb, 262144);
    cvt_f32_bf16<<<1024, 256, 0, stream>>>(wv, wvb, 262144);
    cvt_f32_bf16<<<1024, 256, 0, stream>>>(wo, wob, 262144);
    mask_to_bits<<<16384, 256, 0, stream>>>(mask, bits);
    gemm_qkv<<<dim3(24, 32), 256, 0, stream>>>(xq, xk, xv, wqb, wkb, wvb,
                                               bq, bk, bv, Qb, Kb, VTb);
    attn_kernel<<<dim3(8, 16, 4), 256, 0, stream>>>(Qb, Kb, VTb, bits, Xattn);
    gemm_out<<<dim3(8, 32), 256, 0, stream>>>(Xattn, wob, bo, out);
}

// Round 6
// 255.454 us; speedup vs baseline: 1.2304x; 1.2304x over previous
//
#include <hip/hip_runtime.h>

// MHA: B=4, S=1024, D=1024, H=16, DK=64
// prep (cvt+mask, 1 launch) -> fused QKV GEMM -> flash attn (no-max softmax) -> out GEMM
// Staging: register round-trip + XOR-swizzled LDS (round-1-verified pattern).
// prep block budget: activations 4096 blocks EACH (1,048,576 f32x4), weights 1024 each.

typedef __attribute__((ext_vector_type(8))) short short8;
typedef __attribute__((ext_vector_type(4))) float f32x4;
typedef __attribute__((ext_vector_type(4))) unsigned short u16x4;
typedef unsigned short u16;
typedef unsigned long long u64;

#define SCALE_Q 0.180336880f  // 0.125 * log2(e); folded into Q at projection

__device__ __forceinline__ u16 f2bf(float f) {
    unsigned u = __float_as_uint(f);
    return (u16)((u + 0x7FFFu + ((u >> 16) & 1u)) >> 16);
}

// ---------------- fused prep: 7x f32->bf16 cvt + mask->bits ----------------
// blocks 0..12287: q/k/v cvt, 4096 blocks per tensor (1024 f32x4 per block)
// blocks 12288..16383: wq/wk/wv/wo cvt, 1024 blocks per tensor
// blocks 16384..20479: mask (1024 ints each)
__global__ __launch_bounds__(256) void prep(
    const float* __restrict__ q, const float* __restrict__ k,
    const float* __restrict__ v, const float* __restrict__ wq,
    const float* __restrict__ wk, const float* __restrict__ wv,
    const float* __restrict__ wo, const int* __restrict__ mask,
    u16* __restrict__ xq, u16* __restrict__ xk, u16* __restrict__ xv,
    u16* __restrict__ wqb, u16* __restrict__ wkb, u16* __restrict__ wvb,
    u16* __restrict__ wob, u64* __restrict__ bits) {
    int bid = blockIdx.x;
    if (bid < 16384) {
        const float* src; u16* dst; int i;
        if (bid < 12288) {
            int chunk = bid >> 12;      // 0..2
            int off = bid & 4095;       // 4096 blocks/tensor
            src = (chunk == 0) ? q : ((chunk == 1) ? k : v);
            dst = (chunk == 0) ? xq : ((chunk == 1) ? xk : xv);
            i = off * 256 + threadIdx.x;   // 0..1048575 f32x4
        } else {
            int wb = bid - 12288;
            int chunk = wb >> 10;       // 0..3
            int off = wb & 1023;        // 1024 blocks/tensor
            src = (chunk == 0) ? wq : ((chunk == 1) ? wk : ((chunk == 2) ? wv : wo));
            dst = (chunk == 0) ? wqb : ((chunk == 1) ? wkb : ((chunk == 2) ? wvb : wob));
            i = off * 256 + threadIdx.x;   // 0..262143 f32x4
        }
        f32x4 val = ((const f32x4*)src)[i];
        u16x4 r;
        r.x = f2bf(val.x); r.y = f2bf(val.y); r.z = f2bf(val.z); r.w = f2bf(val.w);
        ((u16x4*)dst)[i] = r;
    } else {
        int mb = bid - 16384;   // 0..4095, 1024 ints each -> 4M total
        int wid = threadIdx.x >> 6, lane = threadIdx.x & 63;
        int base = mb * 1024 + wid * 256;
        #pragma unroll
        for (int j = 0; j < 4; ++j) {
            u64 bal = __ballot(mask[base + j * 64 + lane] != 0);
            if (lane == 0) bits[(base >> 6) + j] = bal;
        }
    }
}

// ---------------- GEMM core: C[128x128] = A[128xK] * B[128xK]^T ----------------
// Register staging + XOR-swizzled LDS (round-1 verified).
__device__ __forceinline__ void gemm_core_128(const u16* __restrict__ A,
                                              const u16* __restrict__ B,
                                              int m0, int n0,
                                              u16* As, u16* Bs,
                                              f32x4 acc[4][4]) {
    const int t = threadIdx.x;
    const int lane = t & 63;
    const int wid = t >> 6;
    const int l15 = lane & 15;
    const int quad = lane >> 4;
    const int wm = (wid & 1) * 64;
    const int wn = (wid >> 1) * 64;
    const int sr = t >> 3;   // 0..31
    const int sc = t & 7;    // 16B granule

    for (int kt = 0; kt < 1024; kt += 64) {
        __syncthreads();
        #pragma unroll
        for (int p = 0; p < 4; ++p) {
            int r = p * 32 + sr;
            int gl = sc ^ (r & 7);
            *(short8*)&As[r * 64 + gl * 8] =
                *(const short8*)&A[(size_t)(m0 + r) * 1024 + kt + sc * 8];
            *(short8*)&Bs[r * 64 + gl * 8] =
                *(const short8*)&B[(size_t)(n0 + r) * 1024 + kt + sc * 8];
        }
        __syncthreads();
        #pragma unroll
        for (int ks = 0; ks < 2; ++ks) {
            short8 af[4], bf[4];
            #pragma unroll
            for (int i = 0; i < 4; ++i) {
                int mr = wm + i * 16 + l15;
                af[i] = *(const short8*)&As[mr * 64 + (((ks << 2) + quad) ^ (mr & 7)) * 8];
                int nr = wn + i * 16 + l15;
                bf[i] = *(const short8*)&Bs[nr * 64 + (((ks << 2) + quad) ^ (nr & 7)) * 8];
            }
            #pragma unroll
            for (int mi = 0; mi < 4; ++mi)
                #pragma unroll
                for (int ni = 0; ni < 4; ++ni)
                    acc[mi][ni] = __builtin_amdgcn_mfma_f32_16x16x32_bf16(
                        af[mi], bf[ni], acc[mi][ni], 0, 0, 0);
        }
    }
}

// ---------------- fused QKV projection GEMM ----------------
// grid.x = 24 (8 n-tiles x 3 problems), grid.y = 32 (m-tiles)
// p=0 -> Q*scale [B,H,S,DK]; p=1 -> K [B,H,S,DK]; p=2 -> V^T [B,H,DK,S]
__global__ __launch_bounds__(256) void gemm_qkv(
    const u16* __restrict__ Aq, const u16* __restrict__ Ak, const u16* __restrict__ Av,
    const u16* __restrict__ Wq, const u16* __restrict__ Wk, const u16* __restrict__ Wv,
    const float* __restrict__ bq, const float* __restrict__ bk, const float* __restrict__ bv,
    u16* __restrict__ Qo, u16* __restrict__ Ko, u16* __restrict__ VTo) {
    __shared__ __align__(16) u16 As[128 * 64];
    __shared__ __align__(16) u16 Bs[128 * 64];
    const int bn = blockIdx.x;
    const int p = bn >> 3;
    const int n0 = (bn & 7) * 128;
    const int m0 = blockIdx.y * 128;
    const u16* A = (p == 0) ? Aq : ((p == 1) ? Ak : Av);
    const u16* W = (p == 0) ? Wq : ((p == 1) ? Wk : Wv);
    const float* bias = (p == 0) ? bq : ((p == 1) ? bk : bv);

    f32x4 acc[4][4];
    #pragma unroll
    for (int i = 0; i < 4; ++i)
        #pragma unroll
        for (int j = 0; j < 4; ++j) acc[i][j] = (f32x4){0.f, 0.f, 0.f, 0.f};

    gemm_core_128(A, W, m0, n0, As, Bs, acc);

    const int lane = threadIdx.x & 63;
    const int wid = threadIdx.x >> 6;
    const int l15 = lane & 15;
    const int quad = lane >> 4;
    const int wm = (wid & 1) * 64;
    const int wn = (wid >> 1) * 64;
    u16* dst01 = (p == 0) ? Qo : Ko;
    const float qs = (p == 0) ? SCALE_Q : 1.0f;

    #pragma unroll
    for (int mi = 0; mi < 4; ++mi) {
        #pragma unroll
        for (int ni = 0; ni < 4; ++ni) {
            int col = n0 + wn + ni * 16 + l15;  // 0..1023
            int h = col >> 6, dk = col & 63;
            float bcol = bias[col];
            if (p < 2) {
                #pragma unroll
                for (int r = 0; r < 4; ++r) {
                    int row = m0 + wm + mi * 16 + quad * 4 + r;
                    int bb = row >> 10, s = row & 1023;
                    dst01[(size_t)((bb * 16 + h) * 1024 + s) * 64 + dk] =
                        f2bf((acc[mi][ni][r] + bcol) * qs);
                }
            } else {
                int row0 = m0 + wm + mi * 16 + quad * 4;
                int bb = row0 >> 10, s0 = row0 & 1023;
                u64 pk = 0;
                #pragma unroll
                for (int r = 0; r < 4; ++r)
                    pk |= (u64)f2bf(acc[mi][ni][r] + bcol) << (16 * r);
                *(u64*)&VTo[(size_t)((bb * 16 + h) * 64 + dk) * 1024 + s0] = pk;
            }
        }
    }
}

// ---------------- output projection GEMM (64x128 tiles) ----------------
__global__ __launch_bounds__(256) void gemm_out(
    const u16* __restrict__ X, const u16* __restrict__ Wo,
    const float* __restrict__ bo, float* __restrict__ out) {
    __shared__ __align__(16) u16 As[64 * 64];
    __shared__ __align__(16) u16 Bs[128 * 64];
    const int n0 = blockIdx.x * 128;
    const int m0 = blockIdx.y * 64;
    const int t = threadIdx.x;
    const int lane = t & 63;
    const int wid = t >> 6;
    const int l15 = lane & 15;
    const int quad = lane >> 4;
    const int wm = (wid & 1) * 32;
    const int wn = (wid >> 1) * 64;
    const int sr = t >> 3;
    const int sc = t & 7;

    f32x4 acc[2][4];
    #pragma unroll
    for (int i = 0; i < 2; ++i)
        #pragma unroll
        for (int j = 0; j < 4; ++j) acc[i][j] = (f32x4){0.f, 0.f, 0.f, 0.f};

    for (int kt = 0; kt < 1024; kt += 64) {
        __syncthreads();
        // A: 64 rows (2 passes)
        #pragma unroll
        for (int p = 0; p < 2; ++p) {
            int r = p * 32 + sr;
            int gl = sc ^ (r & 7);
            *(short8*)&As[r * 64 + gl * 8] =
                *(const short8*)&X[(size_t)(m0 + r) * 1024 + kt + sc * 8];
        }
        // B: 128 rows (4 passes)
        #pragma unroll
        for (int p = 0; p < 4; ++p) {
            int r = p * 32 + sr;
            int gl = sc ^ (r & 7);
            *(short8*)&Bs[r * 64 + gl * 8] =
                *(const short8*)&Wo[(size_t)(n0 + r) * 1024 + kt + sc * 8];
        }
        __syncthreads();
        #pragma unroll
        for (int ks = 0; ks < 2; ++ks) {
            short8 af[2], bf[4];
            #pragma unroll
            for (int i = 0; i < 2; ++i) {
                int mr = wm + i * 16 + l15;
                af[i] = *(const short8*)&As[mr * 64 + (((ks << 2) + quad) ^ (mr & 7)) * 8];
            }
            #pragma unroll
            for (int j = 0; j < 4; ++j) {
                int nr = wn + j * 16 + l15;
                bf[j] = *(const short8*)&Bs[nr * 64 + (((ks << 2) + quad) ^ (nr & 7)) * 8];
            }
            #pragma unroll
            for (int mi = 0; mi < 2; ++mi)
                #pragma unroll
                for (int ni = 0; ni < 4; ++ni)
                    acc[mi][ni] = __builtin_amdgcn_mfma_f32_16x16x32_bf16(
                        af[mi], bf[ni], acc[mi][ni], 0, 0, 0);
        }
    }

    #pragma unroll
    for (int mi = 0; mi < 2; ++mi) {
        #pragma unroll
        for (int ni = 0; ni < 4; ++ni) {
            int col = n0 + wn + ni * 16 + l15;
            float bcol = bo[col];
            #pragma unroll
            for (int r = 0; r < 4; ++r) {
                int row = m0 + wm + mi * 16 + quad * 4 + r;
                out[(size_t)row * 1024 + col] = acc[mi][ni][r] + bcol;
            }
        }
    }
}

// ---------------- flash attention, no-max softmax ----------------
// grid: (16 q-tiles of 64, 16 heads, 4 batch). 4 waves, each 16 q-rows.
// Q pre-scaled by 0.125*log2e; p = exp2(s) masked; l summed lazily.
__global__ __launch_bounds__(256) void attn_kernel(
    const u16* __restrict__ Q, const u16* __restrict__ K, const u16* __restrict__ VT,
    const u64* __restrict__ mbits, u16* __restrict__ X) {
    __shared__ __align__(16) u16 Qs[64 * 64];
    __shared__ __align__(16) u16 Ks[64 * 64];
    __shared__ __align__(16) u16 Vs[64 * 64];
    __shared__ __align__(16) u16 Ps[4][16 * 72];  // per-wave P, stride 72

    const int qt = blockIdx.x;
    const int h = blockIdx.y;
    const int b = blockIdx.z;
    const int t = threadIdx.x;
    const int lane = t & 63;
    const int wid = t >> 6;
    const int l15 = lane & 15;
    const int quad = lane >> 4;
    const int q0 = qt * 64;
    const int sr = t >> 3;
    const int sc = t & 7;

    const size_t headoff = (size_t)(b * 16 + h) * 1024 * 64;
    const u16* Qh = Q + headoff;
    const u16* Kh = K + headoff;
    const u16* Vh = VT + headoff;  // [64][1024]

    // stage the 64-row Q tile once (swizzled, 2 passes)
    #pragma unroll
    for (int p = 0; p < 2; ++p) {
        int r = p * 32 + sr;
        int gl = sc ^ (r & 7);
        *(short8*)&Qs[r * 64 + gl * 8] =
            *(const short8*)&Qh[(size_t)(q0 + r) * 64 + sc * 8];
    }

    f32x4 o_acc[4];
    #pragma unroll
    for (int j = 0; j < 4; ++j) o_acc[j] = (f32x4){0.f, 0.f, 0.f, 0.f};
    float lacc[4] = {0.f, 0.f, 0.f, 0.f};

    // mask word base for this lane's 4 rows: row = q0 + wid*16 + quad*4 + r
    const u64* mrow = &mbits[(size_t)((b << 10) + q0 + wid * 16 + quad * 4) << 4];

    for (int kt = 0; kt < 16; ++kt) {
        const int kv0 = kt * 64;
        __syncthreads();
        // stage K tile [64][64] + V^T tile [64 d][64 kv] (swizzled, 2 passes each)
        #pragma unroll
        for (int p = 0; p < 2; ++p) {
            int r = p * 32 + sr;
            int gl = sc ^ (r & 7);
            *(short8*)&Ks[r * 64 + gl * 8] =
                *(const short8*)&Kh[(size_t)(kv0 + r) * 64 + sc * 8];
            *(short8*)&Vs[r * 64 + gl * 8] =
                *(const short8*)&Vh[(size_t)r * 1024 + kv0 + sc * 8];
        }
        __syncthreads();

        // S = Q K^T : wave computes 16 q-rows x 64 kv-cols
        f32x4 sacc[4];
        #pragma unroll
        for (int j = 0; j < 4; ++j) sacc[j] = (f32x4){0.f, 0.f, 0.f, 0.f};
        #pragma unroll
        for (int ks = 0; ks < 2; ++ks) {
            int m = wid * 16 + l15;
            short8 qf = *(const short8*)&Qs[m * 64 + (((ks << 2) + quad) ^ (m & 7)) * 8];
            #pragma unroll
            for (int j = 0; j < 4; ++j) {
                int n = j * 16 + l15;
                short8 kf = *(const short8*)&Ks[n * 64 + (((ks << 2) + quad) ^ (n & 7)) * 8];
                sacc[j] = __builtin_amdgcn_mfma_f32_16x16x32_bf16(qf, kf, sacc[j], 0, 0, 0);
            }
        }

        // masked exp2, accumulate l per-lane, P -> per-wave LDS (bf16)
        #pragma unroll
        for (int r = 0; r < 4; ++r) {
            u64 w = mrow[(r << 4) + kt];
            #pragma unroll
            for (int ni = 0; ni < 4; ++ni) {
                float p = exp2f(sacc[ni][r]);
                p = ((w >> (ni * 16 + l15)) & 1ull) ? p : 0.f;
                lacc[r] += p;
                Ps[wid][(quad * 4 + r) * 72 + ni * 16 + l15] = f2bf(p);
            }
        }

        // O += P V (P per-wave LDS A-layout; V^T B-layout)
        #pragma unroll
        for (int ks = 0; ks < 2; ++ks) {
            short8 pf = *(const short8*)&Ps[wid][l15 * 72 + ks * 32 + quad * 8];
            #pragma unroll
            for (int j = 0; j < 4; ++j) {
                int d = j * 16 + l15;
                short8 vf = *(const short8*)&Vs[d * 64 + (((ks << 2) + quad) ^ (d & 7)) * 8];
                o_acc[j] = __builtin_amdgcn_mfma_f32_16x16x32_bf16(pf, vf, o_acc[j], 0, 0, 0);
            }
        }
    }

    // reduce l across the 16 lanes sharing each row, normalize, store
    #pragma unroll
    for (int r = 0; r < 4; ++r) {
        float l = lacc[r];
        l += __shfl_xor(l, 1);
        l += __shfl_xor(l, 2);
        l += __shfl_xor(l, 4);
        l += __shfl_xor(l, 8);
        float inv = 1.0f / l;
        int qrow = q0 + wid * 16 + quad * 4 + r;
        #pragma unroll
        for (int ni = 0; ni < 4; ++ni) {
            X[(size_t)(b * 1024 + qrow) * 1024 + h * 64 + ni * 16 + l15] =
                f2bf(o_acc[ni][r] * inv);
        }
    }
}

// ---------------- launch ----------------
extern "C" void kernel_launch(void* const* d_in, const int* in_sizes, int n_in,
                              void* d_out, int out_size, void* d_ws, size_t ws_size,
                              hipStream_t stream) {
    const float* query = (const float*)d_in[0];
    const float* key_ = (const float*)d_in[1];
    const float* value = (const float*)d_in[2];
    const int* mask = (const int*)d_in[3];
    const float* wq = (const float*)d_in[4];
    const float* bq = (const float*)d_in[5];
    const float* wk = (const float*)d_in[6];
    const float* bk = (const float*)d_in[7];
    const float* wv = (const float*)d_in[8];
    const float* bv = (const float*)d_in[9];
    const float* wo = (const float*)d_in[10];
    const float* bo = (const float*)d_in[11];
    float* out = (float*)d_out;

    char* ws = (char*)d_ws;
    const size_t XB = (size_t)4096 * 1024 * 2;  // 8 MB bf16 activation
    const size_t WB = (size_t)1024 * 1024 * 2;  // 2 MB bf16 weight
    u16* xq = (u16*)(ws);
    u16* xk = (u16*)(ws + XB);
    u16* xv = (u16*)(ws + 2 * XB);
    u16* wqb = (u16*)(ws + 3 * XB);
    u16* wkb = (u16*)(ws + 3 * XB + WB);
    u16* wvb = (u16*)(ws + 3 * XB + 2 * WB);
    u16* wob = (u16*)(ws + 3 * XB + 3 * WB);
    u16* Qb = (u16*)(ws + 3 * XB + 4 * WB);
    u16* Kb = (u16*)(ws + 4 * XB + 4 * WB);
    u16* VTb = (u16*)(ws + 5 * XB + 4 * WB);
    u64* bits = (u64*)(ws + 6 * XB + 4 * WB);
    u16* Xattn = xq;  // xq dead after gemm_qkv

    prep<<<20480, 256, 0, stream>>>(query, key_, value, wq, wk, wv, wo, mask,
                                    xq, xk, xv, wqb, wkb, wvb, wob, bits);
    gemm_qkv<<<dim3(24, 32), 256, 0, stream>>>(xq, xk, xv, wqb, wkb, wvb,
                                               bq, bk, bv, Qb, Kb, VTb);
    attn_kernel<<<dim3(16, 16, 4), 256, 0, stream>>>(Qb, Kb, VTb, bits, Xattn);
    gemm_out<<<dim3(8, 64), 256, 0, stream>>>(Xattn, wob, bo, out);
}